// Round 7
// baseline (801.514 us; speedup 1.0000x reference)
//
#include <hip/hip_runtime.h>

#define CH 128
#define PIXTOT (4*256*256)   // 262144
#define L2E 1.4426950408889634f

typedef unsigned short u16;
typedef short short8 __attribute__((ext_vector_type(8)));
typedef float f32x4 __attribute__((ext_vector_type(4)));

__device__ __forceinline__ float bf2f(u16 u){ return __uint_as_float(((unsigned)u)<<16); }
__device__ __forceinline__ u16 f2bf(float f){
  return (u16)((__float_as_uint(f) + 0x8000u) >> 16);
}
__device__ __forceinline__ unsigned pk2(float a, float b){
  return (unsigned)f2bf(a) | ((unsigned)f2bf(b) << 16);
}
__device__ __forceinline__ float fexp2(float x){ return __builtin_amdgcn_exp2f(x); }
__device__ __forceinline__ float frcp(float x){ return __builtin_amdgcn_rcpf(x); }
__device__ __forceinline__ float sigm(float x){ return frcp(1.f + fexp2(-L2E*x)); }
__device__ __forceinline__ float tanh_f(float x){ return 1.f - 2.f*frcp(fexp2(2.f*L2E*x)+1.f); }
__device__ __forceinline__ float pade_tanh(float c){   // |c|<1, err <2e-6
  float c2 = c*c, c4 = c2*c2;
  float p  = __builtin_fmaf(c2, 105.f, 945.f) + c4;
  float q  = __builtin_fmaf(c4, 15.f, __builtin_fmaf(c2, 420.f, 945.f));
  return c * p * frcp(q);
}

// ---------------------------------------------------------------------------
// Weight prep (once per launch):
//  W0c/W1c [384][128] bf16: live LSTM gates (i,g,o), pre-scaled (-L2E,2L2E,-L2E)
//  b0c/b1c [384] fp32 same scaling.
//  Wmc [128][128] bf16: Wmsg e-part.
//  Wuv [256][128] bf16: rows 0..127 = Wmsg[:,0:128], 128..255 = Wmsg[:,128:256]
//  Wg1 [768][128] bf16: rows 0..383 = Wih1, 384..767 = Whh1
__global__ __launch_bounds__(256) void wcvt_kernel(
    const float* __restrict__ W0, const float* __restrict__ bl0,
    const float* __restrict__ W1, const float* __restrict__ bl1,
    const float* __restrict__ Wm,
    const float* __restrict__ Wih1, const float* __restrict__ Whh1,
    u16* __restrict__ W0c, u16* __restrict__ W1c,
    float* __restrict__ b0c, float* __restrict__ b1c,
    u16* __restrict__ Wmc, u16* __restrict__ Wuv, u16* __restrict__ Wg1)
{
  int idx = blockIdx.x*256 + threadIdx.x;   // grid covers 98304
  int col = idx & 127;
  if (idx < 49152){
    int row = idx >> 7;
    int slot = row >> 7;
    int src = (row < 128) ? row : row + 128;  // i, g, o source rows
    float s = (slot == 1) ? (2.f*L2E) : (-L2E);
    W0c[idx] = f2bf(W0[(size_t)src*256 + col] * s);
    W1c[idx] = f2bf(W1[(size_t)src*256 + col] * s);
  }
  if (idx < 16384)
    Wmc[idx] = f2bf(Wm[(size_t)(idx>>7)*384 + 256 + col]);
  if (idx < 32768){
    int row = idx >> 7;
    Wuv[idx] = (row < 128) ? f2bf(Wm[(size_t)row*384 + col])
                           : f2bf(Wm[(size_t)(row-128)*384 + 128 + col]);
  }
  {
    int row = idx >> 7;
    Wg1[idx] = (row < 384) ? f2bf(Wih1[(size_t)row*128 + col])
                           : f2bf(Whh1[(size_t)(row-384)*128 + col]);
  }
  if (idx < 384){
    int row = idx;
    int src = (row < 128) ? row : row + 128;
    float s = ((row>>7) == 1) ? (2.f*L2E) : (-L2E);
    b0c[idx] = bl0[src] * s;
    b1c[idx] = bl1[src] * s;
  }
}

// ---------------------------------------------------------------------------
// Stage a 64-row x 128-ch tile from channel-major source (stride 256 rows)
// into xs[row][ch] bf16.  base = src + (chan)*256 + row0.
__device__ __forceinline__ void stage_cmaj(
    const float* __restrict__ base, u16 (*xs)[136], int t)
{
  const int c = t >> 1, ph = (t & 1) * 32;
  const float* src = base + (size_t)c*256 + ph;
  #pragma unroll
  for (int j=0; j<8; j++){
    f32x4 v = *(const f32x4*)(src + j*4);
    u16* dst = &xs[ph + j*4][c];
    dst[0*136]=f2bf(v[0]); dst[1*136]=f2bf(v[1]);
    dst[2*136]=f2bf(v[2]); dst[3*136]=f2bf(v[3]);
  }
}

// ---------------------------------------------------------------------------
// uv via MFMA: U[b][i][o] = Wmsg[:,0:128].nf[b,:,i] + bmsg; V = Wmsg[:,128:256].nf
__global__ __launch_bounds__(256) void uvmfma_kernel(
    const float* __restrict__ nf, const u16* __restrict__ Wuv,
    const float* __restrict__ bmsg, float* __restrict__ U, float* __restrict__ V)
{
  const int b = blockIdx.x >> 2, i0 = (blockIdx.x & 3) * 64;
  __shared__ u16 xs[64][136];
  const int t = threadIdx.x;
  stage_cmaj(nf + (size_t)b*CH*256 + i0, xs, t);
  __syncthreads();
  const int wv = t >> 6, lane = t & 63, lm = lane & 15, quad = lane >> 4;
  f32x4 acc[4][4];
  #pragma unroll
  for (int rs=0; rs<4; rs++)
    #pragma unroll
    for (int nt=0; nt<4; nt++){ f32x4 z={0.f,0.f,0.f,0.f}; acc[rs][nt]=z; }
  #pragma unroll
  for (int k0=0; k0<128; k0+=32){
    short8 bfr[4];
    #pragma unroll
    for (int nt=0; nt<4; nt++)
      bfr[nt] = *(const short8*)&xs[nt*16+lm][k0 + quad*8];
    #pragma unroll
    for (int rs=0; rs<4; rs++){
      const short8 afr = *(const short8*)(Wuv + ((size_t)(wv*64 + rs*16 + lm))*128 + k0 + quad*8);
      #pragma unroll
      for (int nt=0; nt<4; nt++)
        acc[rs][nt] = __builtin_amdgcn_mfma_f32_16x16x32_bf16(afr, bfr[nt], acc[rs][nt], 0,0,0);
    }
  }
  #pragma unroll
  for (int rs=0; rs<4; rs++){
    const int row0 = wv*64 + rs*16 + quad*4;
    #pragma unroll
    for (int nt=0; nt<4; nt++){
      const int i = i0 + nt*16 + lm;
      #pragma unroll
      for (int r=0; r<4; r++){
        const int row = row0 + r;
        if (row < 128) U[((size_t)(b*256 + i))*CH + row] = acc[rs][nt][r] + bmsg[row];
        else           V[((size_t)(b*256 + i))*CH + row - 128] = acc[rs][nt][r];
      }
    }
  }
}

// ---------------------------------------------------------------------------
// One LSTM layer, per-gate K-loops (acc = 32 AGPR). Gates pre-scaled so
// exp2 is bare. sig_i then tanh(c) carried as packed bf16 (16 VGPRs).
// LAST=false: write bf16 x to xout. LAST=true: accumulate Wo-dot partials.
template<bool LAST>
__device__ __forceinline__ void lstm_layer(
    const u16 (*xin)[136], u16 (*xout)[136],
    const u16* __restrict__ W, const float* __restrict__ Bc,
    int oc0, int lm, int quad, const float woc[2][4], float* partial)
{
  unsigned tp[2][4][2];
  #pragma unroll
  for (int g=0; g<3; g++){
    f32x4 acc[2][4];
    #pragma unroll
    for (int rs=0; rs<2; rs++)
      #pragma unroll
      for (int nt=0; nt<4; nt++){ f32x4 z={0.f,0.f,0.f,0.f}; acc[rs][nt]=z; }
    #pragma unroll
    for (int k0=0; k0<128; k0+=32){
      short8 bfr[4];
      #pragma unroll
      for (int nt=0; nt<4; nt++)
        bfr[nt] = *(const short8*)&xin[nt*16+lm][k0 + quad*8];
      #pragma unroll
      for (int rs=0; rs<2; rs++){
        const short8 afr = *(const short8*)(W + ((size_t)(g*128 + oc0 + rs*16 + lm))*128 + k0 + quad*8);
        #pragma unroll
        for (int nt=0; nt<4; nt++)
          acc[rs][nt] = __builtin_amdgcn_mfma_f32_16x16x32_bf16(afr, bfr[nt], acc[rs][nt], 0,0,0);
      }
    }
    #pragma unroll
    for (int rs=0; rs<2; rs++){
      float bi[4];
      #pragma unroll
      for (int r=0; r<4; r++) bi[r] = Bc[g*128 + oc0 + rs*16 + quad*4 + r];
      #pragma unroll
      for (int nt=0; nt<4; nt++){
        if (g == 0){
          float s0 = frcp(1.f + fexp2(acc[rs][nt][0] + bi[0]));
          float s1 = frcp(1.f + fexp2(acc[rs][nt][1] + bi[1]));
          float s2 = frcp(1.f + fexp2(acc[rs][nt][2] + bi[2]));
          float s3 = frcp(1.f + fexp2(acc[rs][nt][3] + bi[3]));
          tp[rs][nt][0] = pk2(s0, s1);
          tp[rs][nt][1] = pk2(s2, s3);
        } else if (g == 1){
          #pragma unroll
          for (int pr=0; pr<2; pr++){
            float t1a = bf2f((u16)tp[rs][nt][pr]);
            float t1b = bf2f((u16)(tp[rs][nt][pr] >> 16));
            float ga = fminf(acc[rs][nt][pr*2]   + bi[pr*2],   80.f);
            float gb = fminf(acc[rs][nt][pr*2+1] + bi[pr*2+1], 80.f);
            float ea = fexp2(ga), eb = fexp2(gb);
            float ca = t1a * (ea - 1.f) * frcp(ea + 1.f);
            float cb = t1b * (eb - 1.f) * frcp(eb + 1.f);
            tp[rs][nt][pr] = pk2(pade_tanh(ca), pade_tanh(cb));
          }
        } else {
          float xo[4];
          #pragma unroll
          for (int pr=0; pr<2; pr++){
            float tca = bf2f((u16)tp[rs][nt][pr]);
            float tcb = bf2f((u16)(tp[rs][nt][pr] >> 16));
            float fa = fexp2(acc[rs][nt][pr*2]   + bi[pr*2]);
            float fb = fexp2(acc[rs][nt][pr*2+1] + bi[pr*2+1]);
            xo[pr*2]   = tca * frcp(1.f + fa);
            xo[pr*2+1] = tcb * frcp(1.f + fb);
          }
          if (LAST){
            #pragma unroll
            for (int r=0; r<4; r++)
              partial[nt] = __builtin_fmaf(xo[r], woc[rs][r], partial[nt]);
          } else {
            ushort4 w4;
            #pragma unroll
            for (int r=0; r<4; r++) ((u16*)&w4)[r] = f2bf(xo[r]);
            *(ushort4*)&xout[nt*16+lm][oc0 + rs*16 + quad*4] = w4;
          }
        }
      }
    }
  }
}

// ---------------------------------------------------------------------------
// Fused link rounds, 64-px tiles. MODE 0: input = edge tile.
// MODE 1: input = (Wmsg_e.edge + U + V)*A1; also scatters final A + A2nat.
template<int MODE>
__global__ __launch_bounds__(256, 4) void link_kernel(
    const float* __restrict__ edge, const float* __restrict__ A1,
    const float* __restrict__ U, const float* __restrict__ V,
    const u16* __restrict__ Wmc,
    const u16* __restrict__ W0c, const float* __restrict__ B0c,
    const u16* __restrict__ W1c, const float* __restrict__ B1c,
    const float* __restrict__ Wo, const float* __restrict__ Bo,
    float* __restrict__ Aout, float* __restrict__ outA, float* __restrict__ A2nat)
{
  __shared__ u16 xs[64][136];
  __shared__ u16 ys[64][136];
  __shared__ float red[64][17];
  const int t = threadIdx.x;
  const int Q0 = blockIdx.x * 64;
  const int b = Q0 >> 16, q1 = (Q0 >> 8) & 255, w0 = Q0 & 255;
  stage_cmaj(edge + ((size_t)b*CH*256 + q1)*256 + w0, xs, t);
  const int wv = t >> 6, lane = t & 63, lm = lane & 15, quad = lane >> 4;
  const int oc0 = wv*32;
  float woc[2][4];
  #pragma unroll
  for (int rs=0; rs<2; rs++){
    const f32x4 wv4 = *(const f32x4*)(Wo + oc0 + rs*16 + quad*4);
    #pragma unroll
    for (int r=0; r<4; r++) woc[rs][r] = wv4[r];
  }
  __syncthreads();
  if (MODE){
    f32x4 acc[2][4];
    #pragma unroll
    for (int rs=0; rs<2; rs++)
      #pragma unroll
      for (int nt=0; nt<4; nt++){ f32x4 z={0.f,0.f,0.f,0.f}; acc[rs][nt]=z; }
    #pragma unroll
    for (int k0=0; k0<128; k0+=32){
      short8 bfr[4];
      #pragma unroll
      for (int nt=0; nt<4; nt++)
        bfr[nt] = *(const short8*)&xs[nt*16+lm][k0 + quad*8];
      #pragma unroll
      for (int rs=0; rs<2; rs++){
        const short8 afr = *(const short8*)(Wmc + ((size_t)(oc0 + rs*16 + lm))*128 + k0 + quad*8);
        #pragma unroll
        for (int nt=0; nt<4; nt++)
          acc[rs][nt] = __builtin_amdgcn_mfma_f32_16x16x32_bf16(afr, bfr[nt], acc[rs][nt], 0,0,0);
      }
    }
    #pragma unroll
    for (int rs=0; rs<2; rs++){
      const int o0 = oc0 + rs*16 + quad*4;
      const f32x4 ug = *(const f32x4*)(U + ((size_t)(b*256 + q1))*CH + o0);
      #pragma unroll
      for (int nt=0; nt<4; nt++){
        const int px = nt*16 + lm;
        const float a1 = A1[Q0 + px];
        const f32x4 vg = *(const f32x4*)(V + ((size_t)(b*256 + w0 + px))*CH + o0);
        ushort4 w4;
        #pragma unroll
        for (int r=0; r<4; r++)
          ((u16*)&w4)[r] = f2bf((acc[rs][nt][r] + ug[r] + vg[r]) * a1);
        *(ushort4*)&ys[px][o0] = w4;
      }
    }
    __syncthreads();
  }
  const u16 (*in0)[136] = MODE ? (const u16(*)[136])ys : (const u16(*)[136])xs;
  u16 (*buf)[136] = MODE ? xs : ys;
  float partial[4] = {0.f, 0.f, 0.f, 0.f};
  lstm_layer<false>(in0, buf, W0c, B0c, oc0, lm, quad, woc, partial);
  __syncthreads();
  lstm_layer<true>((const u16(*)[136])buf, (u16(*)[136])nullptr, W1c, B1c, oc0, lm, quad, woc, partial);
  #pragma unroll
  for (int nt=0; nt<4; nt++) red[nt*16+lm][wv*4+quad] = partial[nt];
  __syncthreads();
  if (t < 64){
    float s = Bo[0];
    #pragma unroll
    for (int k=0; k<16; k++) s += red[t][k];
    const float sg = sigm(s);
    Aout[Q0 + t] = sg;
    if (MODE){
      const size_t p = (size_t)b*65536 + (size_t)(w0 + t)*256 + q1;
      outA[p]  = sg;
      A2nat[p] = sg;
    }
  }
}

// ---------------------------------------------------------------------------
// Weighted edge row-sum: s_e[b,i,c] = sum_w e[b,c,i,w]*A2nat[b,i,w]; sA = sum_w A2.
__global__ __launch_bounds__(256) void se_kernel(
    const float* __restrict__ edge, const float* __restrict__ A2nat,
    float* __restrict__ s_e, float* __restrict__ sA)
{
  const int b = blockIdx.x >> 8, i = blockIdx.x & 255;
  __shared__ float al[256];
  __shared__ float sb[2][128];
  __shared__ float rr[64];
  const int t = threadIdx.x;
  al[t] = A2nat[((size_t)(b*256 + i))*256 + t];
  __syncthreads();
  const int c = t & 127, half = t >> 7;
  const float* src = edge + (((size_t)(b*CH + c))*256 + i)*256 + half*128;
  float s = 0.f;
  #pragma unroll
  for (int j=0; j<32; j++){
    const f32x4 v = *(const f32x4*)(src + j*4);
    const float* ap = &al[half*128 + j*4];
    s += v[0]*ap[0] + v[1]*ap[1] + v[2]*ap[2] + v[3]*ap[3];
  }
  sb[half][c] = s;
  if (t < 64) rr[t] = al[t] + al[t+64] + al[t+128] + al[t+192];
  __syncthreads();
  if (t < 128) s_e[((size_t)(b*256 + i))*CH + t] = sb[0][t] + sb[1][t];
  if (t == 0){
    float sa = 0.f;
    for (int k=0; k<64; k++) sa += rr[k];
    sA[b*256 + i] = sa;
  }
}

// ---------------------------------------------------------------------------
// msum[b,i,o] = W3[o,:].s_e + U[b,i,o]*sA + sum_w A2nat[b,i,w]*V[b,w,o]
__global__ __launch_bounds__(128) void mfinal_kernel(
    const float* __restrict__ s_e, const float* __restrict__ sA,
    const float* __restrict__ A2nat, const float* __restrict__ V,
    const float* __restrict__ Wmsg, const float* __restrict__ U,
    float* __restrict__ msum)
{
  const int b = blockIdx.x >> 8, i = blockIdx.x & 255;
  __shared__ float se_s[128];
  __shared__ float al[256];
  const int t = threadIdx.x;
  se_s[t] = s_e[((size_t)(b*256 + i))*CH + t];
  al[t]       = A2nat[((size_t)(b*256 + i))*256 + t];
  al[t + 128] = A2nat[((size_t)(b*256 + i))*256 + t + 128];
  __syncthreads();
  const float* w3 = Wmsg + (size_t)t*384 + 256;
  float s = U[((size_t)(b*256 + i))*CH + t] * sA[b*256 + i];
  #pragma unroll 4
  for (int k=0; k<128; k+=4){
    const f32x4 wv4 = *(const f32x4*)(w3 + k);
    s += wv4[0]*se_s[k] + wv4[1]*se_s[k+1] + wv4[2]*se_s[k+2] + wv4[3]*se_s[k+3];
  }
  const float* vp = V + ((size_t)(b*256))*CH + t;
  #pragma unroll 8
  for (int w=0; w<256; w++)
    s += al[w] * vp[(size_t)w*CH];
  msum[((size_t)(b*256 + i))*CH + t] = s;
}

// ---------------------------------------------------------------------------
// GRU gate GEMMs for all nodes with set-1 weights:
// G[b][n][0:384] = msum[b,n,:].Wih1^T ; G[b][n][384:768] = h[b,n,:].Whh1^T
__global__ __launch_bounds__(256) void gg_kernel(
    const float* __restrict__ msum, const float* __restrict__ nf,
    const u16* __restrict__ Wg1, float* __restrict__ G)
{
  const int b = blockIdx.x >> 2, n0 = (blockIdx.x & 3) * 64;
  __shared__ u16 xs[64][136];
  __shared__ u16 hs[64][136];
  const int t = threadIdx.x;
  {
    const int p = t >> 2, seg = (t & 3) * 32;
    const float* src = msum + ((size_t)(b*256 + n0 + p))*CH + seg;
    #pragma unroll
    for (int j=0; j<8; j++){
      f32x4 v = *(const f32x4*)(src + j*4);
      xs[p][seg+j*4+0]=f2bf(v[0]); xs[p][seg+j*4+1]=f2bf(v[1]);
      xs[p][seg+j*4+2]=f2bf(v[2]); xs[p][seg+j*4+3]=f2bf(v[3]);
    }
  }
  stage_cmaj(nf + (size_t)b*CH*256 + n0, hs, t);
  __syncthreads();
  const int wv = t >> 6, lane = t & 63, lm = lane & 15, quad = lane >> 4;
  #pragma unroll
  for (int half=0; half<2; half++){
    const u16 (*in)[136] = half ? (const u16(*)[136])hs : (const u16(*)[136])xs;
    const u16* Wb = Wg1 + (size_t)half*384*128;
    #pragma unroll
    for (int rs=0; rs<6; rs++){
      f32x4 acc[4];
      #pragma unroll
      for (int nt=0; nt<4; nt++){ f32x4 z={0.f,0.f,0.f,0.f}; acc[nt]=z; }
      #pragma unroll
      for (int k0=0; k0<128; k0+=32){
        short8 bfr[4];
        #pragma unroll
        for (int nt=0; nt<4; nt++)
          bfr[nt] = *(const short8*)&in[nt*16+lm][k0 + quad*8];
        const short8 afr = *(const short8*)(Wb + ((size_t)(wv*96 + rs*16 + lm))*128 + k0 + quad*8);
        #pragma unroll
        for (int nt=0; nt<4; nt++)
          acc[nt] = __builtin_amdgcn_mfma_f32_16x16x32_bf16(afr, bfr[nt], acc[nt], 0,0,0);
      }
      #pragma unroll
      for (int nt=0; nt<4; nt++){
        const int n = n0 + nt*16 + lm;
        #pragma unroll
        for (int r=0; r<4; r++)
          G[((size_t)(b*256 + n))*768 + half*384 + wv*96 + rs*16 + quad*4 + r] = acc[nt][r];
      }
    }
  }
}

// ---------------------------------------------------------------------------
// GRU elementwise + readout. n>0: gates from G (set-1). n==0: direct GEMV set-0.
__global__ __launch_bounds__(128) void k5b_kernel(
    const float* __restrict__ G, const float* __restrict__ msum,
    const float* __restrict__ nf,
    const float* __restrict__ Wih0, const float* __restrict__ Whh0,
    const float* __restrict__ bih0, const float* __restrict__ bhh0,
    const float* __restrict__ bih1, const float* __restrict__ bhh1,
    const float* __restrict__ Wr0, const float* __restrict__ br0,
    const float* __restrict__ Wr1, const float* __restrict__ br1,
    float* __restrict__ outp)
{
  const int blk = blockIdx.x, b = blk >> 8, n = blk & 255;
  __shared__ float gl[768];
  __shared__ float xsh[128], hsh[128], hnew[128], lg[16];
  const int t = threadIdx.x;
  hsh[t] = nf[((size_t)(b*CH + t))*256 + n];
  float gi[3], gh[3];
  if (n == 0){
    xsh[t] = msum[((size_t)(b*256 + n))*CH + t];
    __syncthreads();
    #pragma unroll
    for (int prt=0; prt<3; prt++){
      int row = prt*128 + t;
      const float* wi_ = Wih0 + (size_t)row*CH;
      const float* wh_ = Whh0 + (size_t)row*CH;
      float si = 0.f, sh2 = 0.f;
      for (int k=0; k<128; k+=4){
        f32x4 wv1 = *(const f32x4*)(wi_ + k);
        f32x4 wv2 = *(const f32x4*)(wh_ + k);
        #pragma unroll
        for (int j=0; j<4; j++){ si += wv1[j]*xsh[k+j]; sh2 += wv2[j]*hsh[k+j]; }
      }
      gi[prt] = si + bih0[row];
      gh[prt] = sh2 + bhh0[row];
    }
  } else {
    #pragma unroll
    for (int p=0; p<6; p++) gl[p*128 + t] = G[((size_t)(b*256 + n))*768 + p*128 + t];
    __syncthreads();
    #pragma unroll
    for (int prt=0; prt<3; prt++){
      gi[prt] = gl[prt*128 + t] + bih1[prt*128 + t];
      gh[prt] = gl[384 + prt*128 + t] + bhh1[prt*128 + t];
    }
  }
  float r  = sigm(gi[0] + gh[0]);
  float z  = sigm(gi[1] + gh[1]);
  float ng = tanh_f(gi[2] + r*gh[2]);
  hnew[t] = (1.f - z)*ng + z*hsh[t];
  __syncthreads();
  const int K = n ? 12 : 10;
  const float* Wr = n ? Wr1 : Wr0;  const float* br = n ? br1 : br0;
  if (t < K){
    const float* wr_ = Wr + (size_t)t*CH;
    float s = 0.f;
    for (int k=0; k<128; k+=4){
      f32x4 wv1 = *(const f32x4*)(wr_ + k);
      #pragma unroll
      for (int j=0; j<4; j++) s += wv1[j]*hnew[k+j];
    }
    lg[t] = s + br[t];
  }
  __syncthreads();
  if (t < 12){
    float o = 0.f;
    if (t < K){
      float mx = -1e30f;
      for (int j=0; j<K; j++) mx = fmaxf(mx, lg[j]);
      float se = 0.f;
      for (int j=0; j<K; j++) se += __expf(lg[j] - mx);
      o = lg[t] - mx - __logf(se);
    }
    outp[((size_t)(b*256 + n))*12 + t] = o;
  }
}

// ---------------------------------------------------------------------------
extern "C" void kernel_launch(void* const* d_in, const int* in_sizes, int n_in,
                              void* d_out, int out_size, void* d_ws, size_t ws_size,
                              hipStream_t stream)
{
  (void)in_sizes; (void)n_in; (void)out_size; (void)ws_size;
  const float* edge = (const float*)d_in[0];
  const float* nf   = (const float*)d_in[1];
  const float* Wl0  = (const float*)d_in[5];
  const float* bl0  = (const float*)d_in[6];
  const float* Wl1  = (const float*)d_in[7];
  const float* bl1  = (const float*)d_in[8];
  const float* Wlo  = (const float*)d_in[9];
  const float* blo  = (const float*)d_in[10];
  const float* Wmsg = (const float*)d_in[11];
  const float* bmsg = (const float*)d_in[12];
  const float* Wih0 = (const float*)d_in[13];
  const float* Whh0 = (const float*)d_in[14];
  const float* bih0 = (const float*)d_in[15];
  const float* bhh0 = (const float*)d_in[16];
  const float* Wih1 = (const float*)d_in[17];
  const float* Whh1 = (const float*)d_in[18];
  const float* bih1 = (const float*)d_in[19];
  const float* bhh1 = (const float*)d_in[20];
  const float* Wr0  = (const float*)d_in[21];
  const float* br0  = (const float*)d_in[22];
  const float* Wr1  = (const float*)d_in[23];
  const float* br1  = (const float*)d_in[24];

  char* ws = (char*)d_ws;
  float* A1v   = (float*)(ws);                       // [0,       1048576)
  float* A2nat = (float*)(ws + 1048576);             // [1048576, 2097152)
  float* U     = (float*)(ws + 2097152);             // [2097152, 2621440)
  float* V     = (float*)(ws + 2621440);             // [2621440, 3145728)
  float* msum  = (float*)(ws + 3145728);             // [3145728, 3670016)
  float* s_e   = (float*)(ws + 3670016);             // [3670016, 4194304)
  float* sAr   = (float*)(ws + 4194304);             // [4194304, 4198400)
  u16*   W0c   = (u16*)(ws + 4198400);               // [4198400, 4296704)
  u16*   W1c   = (u16*)(ws + 4296704);               // [4296704, 4395008)
  u16*   Wmc   = (u16*)(ws + 4395008);               // [4395008, 4427776)
  float* b0c   = (float*)(ws + 4427776);             // [4427776, 4429312)
  float* b1c   = (float*)(ws + 4429312);             // [4429312, 4430848)
  u16*   Wuv   = (u16*)(ws + 4430848);               // [4430848, 4496384)
  u16*   Wg1   = (u16*)(ws + 4496384);               // [4496384, 4692992)
  // G (3 MB, fp32) overlays A1v/A2nat/U/V — all dead once gg_kernel runs.
  float* G     = (float*)(ws);

  float* outA = (float*)d_out;
  float* outP = outA + (size_t)PIXTOT;

  wcvt_kernel<<<dim3(384), dim3(256), 0, stream>>>(
      Wl0, bl0, Wl1, bl1, Wmsg, Wih1, Whh1,
      W0c, W1c, b0c, b1c, Wmc, Wuv, Wg1);
  uvmfma_kernel<<<dim3(16), dim3(256), 0, stream>>>(nf, Wuv, bmsg, U, V);
  link_kernel<0><<<dim3(PIXTOT/64), dim3(256), 0, stream>>>(
      edge, (const float*)nullptr, U, V, Wmc, W0c, b0c, W1c, b1c, Wlo, blo,
      A1v, (float*)nullptr, (float*)nullptr);
  link_kernel<1><<<dim3(PIXTOT/64), dim3(256), 0, stream>>>(
      edge, A1v, U, V, Wmc, W0c, b0c, W1c, b1c, Wlo, blo,
      A1v, outA, A2nat);
  se_kernel<<<dim3(4*256), dim3(256), 0, stream>>>(edge, A2nat, s_e, sAr);
  mfinal_kernel<<<dim3(4*256), dim3(128), 0, stream>>>(
      s_e, sAr, A2nat, V, Wmsg, U, msum);
  gg_kernel<<<dim3(16), dim3(256), 0, stream>>>(msum, nf, Wg1, G);
  k5b_kernel<<<dim3(4*256), dim3(128), 0, stream>>>(
      G, msum, nf, Wih0, Whh0, bih0, bhh0, bih1, bhh1,
      Wr0, br0, Wr1, br1, outP);
}

// Round 8
// 619.625 us; speedup vs baseline: 1.2935x; 1.2935x over previous
//
#include <hip/hip_runtime.h>

#define CH 128
#define PIXTOT (4*256*256)   // 262144
#define L2E 1.4426950408889634f

typedef unsigned short u16;
typedef short short8 __attribute__((ext_vector_type(8)));
typedef float f32x4 __attribute__((ext_vector_type(4)));

__device__ __forceinline__ float bf2f(u16 u){ return __uint_as_float(((unsigned)u)<<16); }
__device__ __forceinline__ u16 f2bf(float f){
  return (u16)((__float_as_uint(f) + 0x8000u) >> 16);
}
__device__ __forceinline__ unsigned pk2(float a, float b){
  return (unsigned)f2bf(a) | ((unsigned)f2bf(b) << 16);
}
__device__ __forceinline__ float fexp2(float x){ return __builtin_amdgcn_exp2f(x); }
__device__ __forceinline__ float frcp(float x){ return __builtin_amdgcn_rcpf(x); }
__device__ __forceinline__ float sigm(float x){ return frcp(1.f + fexp2(-L2E*x)); }
__device__ __forceinline__ float tanh_f(float x){ return 1.f - 2.f*frcp(fexp2(2.f*L2E*x)+1.f); }
__device__ __forceinline__ float pade_tanh(float c){   // |c|<1, err <2e-6
  float c2 = c*c, c4 = c2*c2;
  float p  = __builtin_fmaf(c2, 105.f, 945.f) + c4;
  float q  = __builtin_fmaf(c4, 15.f, __builtin_fmaf(c2, 420.f, 945.f));
  return c * p * frcp(q);
}

// ---------------------------------------------------------------------------
// Weight prep (once per launch):
//  W0c/W1c [384][128] bf16: live LSTM gates (i,g,o), pre-scaled (-L2E,2L2E,-L2E)
//  b0c/b1c [384] fp32 same scaling.
//  Wmc [128][128] bf16: Wmsg e-part.   W3T [128k][128o] fp32: its transpose.
//  Wuv [256][128] bf16: rows 0..127 = Wmsg[:,0:128], 128..255 = Wmsg[:,128:256]
//  Wg1 [768][128] bf16: rows 0..383 = Wih1, 384..767 = Whh1
__global__ __launch_bounds__(256) void wcvt_kernel(
    const float* __restrict__ W0, const float* __restrict__ bl0,
    const float* __restrict__ W1, const float* __restrict__ bl1,
    const float* __restrict__ Wm,
    const float* __restrict__ Wih1, const float* __restrict__ Whh1,
    u16* __restrict__ W0c, u16* __restrict__ W1c,
    float* __restrict__ b0c, float* __restrict__ b1c,
    u16* __restrict__ Wmc, float* __restrict__ W3T,
    u16* __restrict__ Wuv, u16* __restrict__ Wg1)
{
  int idx = blockIdx.x*256 + threadIdx.x;   // grid covers 98304
  int col = idx & 127;
  if (idx < 49152){
    int row = idx >> 7;
    int slot = row >> 7;
    int src = (row < 128) ? row : row + 128;  // i, g, o source rows
    float s = (slot == 1) ? (2.f*L2E) : (-L2E);
    W0c[idx] = f2bf(W0[(size_t)src*256 + col] * s);
    W1c[idx] = f2bf(W1[(size_t)src*256 + col] * s);
  }
  if (idx < 16384){
    int o = idx >> 7, k = col;
    float w = Wm[(size_t)o*384 + 256 + k];
    Wmc[idx] = f2bf(w);
    W3T[(size_t)k*128 + o] = w;
  }
  if (idx < 32768){
    int row = idx >> 7;
    Wuv[idx] = (row < 128) ? f2bf(Wm[(size_t)row*384 + col])
                           : f2bf(Wm[(size_t)(row-128)*384 + 128 + col]);
  }
  {
    int row = idx >> 7;
    Wg1[idx] = (row < 384) ? f2bf(Wih1[(size_t)row*128 + col])
                           : f2bf(Whh1[(size_t)(row-384)*128 + col]);
  }
  if (idx < 384){
    int row = idx;
    int src = (row < 128) ? row : row + 128;
    float s = ((row>>7) == 1) ? (2.f*L2E) : (-L2E);
    b0c[idx] = bl0[src] * s;
    b1c[idx] = bl1[src] * s;
  }
}

// ---------------------------------------------------------------------------
// Stage a 64-row x 128-ch tile from channel-major source (row stride 256 floats)
// into xs[row][ch] bf16.  Thread = (8-channel group cg, 4-px group pg).
// Global: 16 lanes x 16B contiguous per channel row; LDS: 4x ds_write_b128.
__device__ __forceinline__ void stage_cmaj(
    const float* __restrict__ base, u16 (*xs)[136], int t)
{
  const int cg = t >> 4, pg = t & 15;
  const int c0 = cg*8, p0 = pg*4;
  float v[8][4];
  #pragma unroll
  for (int cc=0; cc<8; cc++){
    const f32x4 f = *(const f32x4*)(base + (size_t)(c0+cc)*256 + p0);
    v[cc][0]=f[0]; v[cc][1]=f[1]; v[cc][2]=f[2]; v[cc][3]=f[3];
  }
  #pragma unroll
  for (int pp=0; pp<4; pp++){
    unsigned d[4];
    #pragma unroll
    for (int q=0; q<4; q++) d[q] = pk2(v[2*q][pp], v[2*q+1][pp]);
    *(uint4*)&xs[p0+pp][c0] = *(const uint4*)d;
  }
}

// ---------------------------------------------------------------------------
// uv via MFMA: U[b][i][o] = Wmsg[:,0:128].nf[b,:,i] + bmsg; V = Wmsg[:,128:256].nf
__global__ __launch_bounds__(256) void uvmfma_kernel(
    const float* __restrict__ nf, const u16* __restrict__ Wuv,
    const float* __restrict__ bmsg, float* __restrict__ U, float* __restrict__ V)
{
  const int b = blockIdx.x >> 2, i0 = (blockIdx.x & 3) * 64;
  __shared__ u16 xs[64][136];
  const int t = threadIdx.x;
  stage_cmaj(nf + (size_t)b*CH*256 + i0, xs, t);
  __syncthreads();
  const int wv = t >> 6, lane = t & 63, lm = lane & 15, quad = lane >> 4;
  f32x4 acc[4][4];
  #pragma unroll
  for (int rs=0; rs<4; rs++)
    #pragma unroll
    for (int nt=0; nt<4; nt++){ f32x4 z={0.f,0.f,0.f,0.f}; acc[rs][nt]=z; }
  #pragma unroll
  for (int k0=0; k0<128; k0+=32){
    short8 bfr[4];
    #pragma unroll
    for (int nt=0; nt<4; nt++)
      bfr[nt] = *(const short8*)&xs[nt*16+lm][k0 + quad*8];
    #pragma unroll
    for (int rs=0; rs<4; rs++){
      const short8 afr = *(const short8*)(Wuv + ((size_t)(wv*64 + rs*16 + lm))*128 + k0 + quad*8);
      #pragma unroll
      for (int nt=0; nt<4; nt++)
        acc[rs][nt] = __builtin_amdgcn_mfma_f32_16x16x32_bf16(afr, bfr[nt], acc[rs][nt], 0,0,0);
    }
  }
  #pragma unroll
  for (int rs=0; rs<4; rs++){
    const int row0 = wv*64 + rs*16 + quad*4;
    #pragma unroll
    for (int nt=0; nt<4; nt++){
      const int i = i0 + nt*16 + lm;
      f32x4 o = acc[rs][nt];
      if (row0 < 128){
        const f32x4 bm = *(const f32x4*)(bmsg + row0);
        o[0]+=bm[0]; o[1]+=bm[1]; o[2]+=bm[2]; o[3]+=bm[3];
        *(f32x4*)(U + ((size_t)(b*256 + i))*CH + row0) = o;
      } else {
        *(f32x4*)(V + ((size_t)(b*256 + i))*CH + row0 - 128) = o;
      }
    }
  }
}

// ---------------------------------------------------------------------------
// One LSTM layer, per-gate K-loops (acc = 32 AGPR, tp = 32 fp32 VGPR).
// Gates pre-scaled so exp2 is bare.
// LAST=false: write bf16 x to xout. LAST=true: accumulate Wo-dot partials.
template<bool LAST>
__device__ __forceinline__ void lstm_layer(
    const u16 (*xin)[136], u16 (*xout)[136],
    const u16* __restrict__ W, const float* __restrict__ Bc,
    int oc0, int lm, int quad, const float woc[2][4], float* partial)
{
  float tp[2][4][4];
  #pragma unroll
  for (int g=0; g<3; g++){
    f32x4 acc[2][4];
    #pragma unroll
    for (int rs=0; rs<2; rs++)
      #pragma unroll
      for (int nt=0; nt<4; nt++){ f32x4 z={0.f,0.f,0.f,0.f}; acc[rs][nt]=z; }
    #pragma unroll
    for (int k0=0; k0<128; k0+=32){
      short8 bfr[4];
      #pragma unroll
      for (int nt=0; nt<4; nt++)
        bfr[nt] = *(const short8*)&xin[nt*16+lm][k0 + quad*8];
      #pragma unroll
      for (int rs=0; rs<2; rs++){
        const short8 afr = *(const short8*)(W + ((size_t)(g*128 + oc0 + rs*16 + lm))*128 + k0 + quad*8);
        #pragma unroll
        for (int nt=0; nt<4; nt++)
          acc[rs][nt] = __builtin_amdgcn_mfma_f32_16x16x32_bf16(afr, bfr[nt], acc[rs][nt], 0,0,0);
      }
    }
    #pragma unroll
    for (int rs=0; rs<2; rs++){
      float bi[4];
      #pragma unroll
      for (int r=0; r<4; r++) bi[r] = Bc[g*128 + oc0 + rs*16 + quad*4 + r];
      #pragma unroll
      for (int nt=0; nt<4; nt++){
        if (g == 0){
          #pragma unroll
          for (int r=0; r<4; r++)
            tp[rs][nt][r] = frcp(1.f + fexp2(acc[rs][nt][r] + bi[r]));
        } else if (g == 1){
          #pragma unroll
          for (int r=0; r<4; r++){
            float e = fexp2(fminf(acc[rs][nt][r] + bi[r], 80.f));
            float c = tp[rs][nt][r] * (e - 1.f) * frcp(e + 1.f);
            tp[rs][nt][r] = pade_tanh(c);
          }
        } else {
          float xo[4];
          #pragma unroll
          for (int r=0; r<4; r++)
            xo[r] = tp[rs][nt][r] * frcp(1.f + fexp2(acc[rs][nt][r] + bi[r]));
          if (LAST){
            #pragma unroll
            for (int r=0; r<4; r++)
              partial[nt] = __builtin_fmaf(xo[r], woc[rs][r], partial[nt]);
          } else {
            ushort4 w4;
            #pragma unroll
            for (int r=0; r<4; r++) ((u16*)&w4)[r] = f2bf(xo[r]);
            *(ushort4*)&xout[nt*16+lm][oc0 + rs*16 + quad*4] = w4;
          }
        }
      }
    }
  }
}

// ---------------------------------------------------------------------------
// Fused link rounds, 64-px tiles. MODE 0: input = edge tile.
// MODE 1: input = (Wmsg_e.edge + U + V)*A1; also scatters final A + A2nat.
template<int MODE>
__global__ __launch_bounds__(256, 3) void link_kernel(
    const float* __restrict__ edge, const float* __restrict__ A1,
    const float* __restrict__ U, const float* __restrict__ V,
    const u16* __restrict__ Wmc,
    const u16* __restrict__ W0c, const float* __restrict__ B0c,
    const u16* __restrict__ W1c, const float* __restrict__ B1c,
    const float* __restrict__ Wo, const float* __restrict__ Bo,
    float* __restrict__ Aout, float* __restrict__ outA, float* __restrict__ A2nat)
{
  __shared__ u16 xs[64][136];
  __shared__ u16 ys[64][136];
  __shared__ float red[64][17];
  const int t = threadIdx.x;
  const int Q0 = blockIdx.x * 64;
  const int b = Q0 >> 16, q1 = (Q0 >> 8) & 255, w0 = Q0 & 255;
  stage_cmaj(edge + ((size_t)b*CH*256 + q1)*256 + w0, xs, t);
  const int wv = t >> 6, lane = t & 63, lm = lane & 15, quad = lane >> 4;
  const int oc0 = wv*32;
  float woc[2][4];
  #pragma unroll
  for (int rs=0; rs<2; rs++){
    const f32x4 wv4 = *(const f32x4*)(Wo + oc0 + rs*16 + quad*4);
    #pragma unroll
    for (int r=0; r<4; r++) woc[rs][r] = wv4[r];
  }
  __syncthreads();
  if (MODE){
    f32x4 acc[2][4];
    #pragma unroll
    for (int rs=0; rs<2; rs++)
      #pragma unroll
      for (int nt=0; nt<4; nt++){ f32x4 z={0.f,0.f,0.f,0.f}; acc[rs][nt]=z; }
    #pragma unroll
    for (int k0=0; k0<128; k0+=32){
      short8 bfr[4];
      #pragma unroll
      for (int nt=0; nt<4; nt++)
        bfr[nt] = *(const short8*)&xs[nt*16+lm][k0 + quad*8];
      #pragma unroll
      for (int rs=0; rs<2; rs++){
        const short8 afr = *(const short8*)(Wmc + ((size_t)(oc0 + rs*16 + lm))*128 + k0 + quad*8);
        #pragma unroll
        for (int nt=0; nt<4; nt++)
          acc[rs][nt] = __builtin_amdgcn_mfma_f32_16x16x32_bf16(afr, bfr[nt], acc[rs][nt], 0,0,0);
      }
    }
    #pragma unroll
    for (int rs=0; rs<2; rs++){
      const int o0 = oc0 + rs*16 + quad*4;
      const f32x4 ug = *(const f32x4*)(U + ((size_t)(b*256 + q1))*CH + o0);
      #pragma unroll
      for (int nt=0; nt<4; nt++){
        const int px = nt*16 + lm;
        const float a1 = A1[Q0 + px];
        const f32x4 vg = *(const f32x4*)(V + ((size_t)(b*256 + w0 + px))*CH + o0);
        ushort4 w4;
        #pragma unroll
        for (int r=0; r<4; r++)
          ((u16*)&w4)[r] = f2bf((acc[rs][nt][r] + ug[r] + vg[r]) * a1);
        *(ushort4*)&ys[px][o0] = w4;
      }
    }
    __syncthreads();
  }
  const u16 (*in0)[136] = MODE ? (const u16(*)[136])ys : (const u16(*)[136])xs;
  u16 (*buf)[136] = MODE ? xs : ys;
  float partial[4] = {0.f, 0.f, 0.f, 0.f};
  lstm_layer<false>(in0, buf, W0c, B0c, oc0, lm, quad, woc, partial);
  __syncthreads();
  lstm_layer<true>((const u16(*)[136])buf, (u16(*)[136])nullptr, W1c, B1c, oc0, lm, quad, woc, partial);
  #pragma unroll
  for (int nt=0; nt<4; nt++) red[nt*16+lm][wv*4+quad] = partial[nt];
  __syncthreads();
  if (t < 64){
    float s = Bo[0];
    #pragma unroll
    for (int k=0; k<16; k++) s += red[t][k];
    const float sg = sigm(s);
    Aout[Q0 + t] = sg;
    if (MODE){
      const size_t p = (size_t)b*65536 + (size_t)(w0 + t)*256 + q1;
      outA[p]  = sg;
      A2nat[p] = sg;
    }
  }
}

// ---------------------------------------------------------------------------
// Weighted edge row-sum: s_e[b,i,c] = sum_w e[b,c,i,w]*A2nat[b,i,w]; sA = sum A2.
// Coalesced: 8 lanes share one edge row (128B contiguous per 8 lanes).
__global__ __launch_bounds__(256) void se_kernel(
    const float* __restrict__ edge, const float* __restrict__ A2nat,
    float* __restrict__ s_e, float* __restrict__ sA)
{
  const int b = blockIdx.x >> 8, i = blockIdx.x & 255;
  __shared__ float al[256];
  __shared__ float sb[128][9];
  __shared__ float rr[64];
  const int t = threadIdx.x;
  al[t] = A2nat[((size_t)(b*256 + i))*256 + t];
  __syncthreads();
  const int seg = t & 7, cb = t >> 3;   // cb 0..31
  #pragma unroll
  for (int cc=0; cc<4; cc++){
    const int c = cc*32 + cb;
    const float* src = edge + (((size_t)(b*CH + c))*256 + i)*256;
    float s = 0.f;
    #pragma unroll
    for (int j=0; j<8; j++){
      const int idx = j*32 + seg*4;
      const f32x4 v = *(const f32x4*)(src + idx);
      s += v[0]*al[idx] + v[1]*al[idx+1] + v[2]*al[idx+2] + v[3]*al[idx+3];
    }
    sb[c][seg] = s;
  }
  if (t < 64) rr[t] = al[t] + al[t+64] + al[t+128] + al[t+192];
  __syncthreads();
  if (t < 128){
    float s = 0.f;
    #pragma unroll
    for (int k=0; k<8; k++) s += sb[t][k];
    s_e[((size_t)(b*256 + i))*CH + t] = s;
  }
  if (t == 0){
    float sa = 0.f;
    for (int k=0; k<64; k++) sa += rr[k];
    sA[b*256 + i] = sa;
  }
}

// ---------------------------------------------------------------------------
// msum[b,i,o] = W3T[:,o].s_e + U[b,i,o]*sA + sum_w A2nat[b,i,w]*V[b,w,o]
__global__ __launch_bounds__(128) void mfinal_kernel(
    const float* __restrict__ s_e, const float* __restrict__ sA,
    const float* __restrict__ A2nat, const float* __restrict__ V,
    const float* __restrict__ W3T, const float* __restrict__ U,
    float* __restrict__ msum)
{
  const int b = blockIdx.x >> 8, i = blockIdx.x & 255;
  __shared__ float se_s[128];
  __shared__ float al[256];
  const int t = threadIdx.x;
  se_s[t] = s_e[((size_t)(b*256 + i))*CH + t];
  al[t]       = A2nat[((size_t)(b*256 + i))*256 + t];
  al[t + 128] = A2nat[((size_t)(b*256 + i))*256 + t + 128];
  __syncthreads();
  float s = U[((size_t)(b*256 + i))*CH + t] * sA[b*256 + i];
  const float* w3 = W3T + t;
  #pragma unroll 8
  for (int k=0; k<128; k++)
    s += w3[(size_t)k*128] * se_s[k];
  const float* vp = V + ((size_t)(b*256))*CH + t;
  #pragma unroll 8
  for (int w=0; w<256; w++)
    s += al[w] * vp[(size_t)w*CH];
  msum[((size_t)(b*256 + i))*CH + t] = s;
}

// ---------------------------------------------------------------------------
// GRU gate GEMMs for all nodes with set-1 weights:
// G[b][n][0:384] = msum[b,n,:].Wih1^T ; G[b][n][384:768] = h[b,n,:].Whh1^T
__global__ __launch_bounds__(256) void gg_kernel(
    const float* __restrict__ msum, const float* __restrict__ nf,
    const u16* __restrict__ Wg1, float* __restrict__ G)
{
  const int b = blockIdx.x >> 2, n0 = (blockIdx.x & 3) * 64;
  __shared__ u16 xs[64][136];
  __shared__ u16 hs[64][136];
  const int t = threadIdx.x;
  {
    const int p = t >> 2, seg = (t & 3) * 32;
    const float* src = msum + ((size_t)(b*256 + n0 + p))*CH + seg;
    #pragma unroll
    for (int jj=0; jj<2; jj++){
      unsigned d[8];
      #pragma unroll
      for (int q=0; q<4; q++){
        const f32x4 v = *(const f32x4*)(src + jj*16 + q*4);
        d[q*2]   = pk2(v[0], v[1]);
        d[q*2+1] = pk2(v[2], v[3]);
      }
      *(uint4*)&xs[p][seg + jj*16]     = *(const uint4*)d;
      *(uint4*)&xs[p][seg + jj*16 + 8] = *(const uint4*)(d+4);
    }
  }
  stage_cmaj(nf + (size_t)b*CH*256 + n0, hs, t);
  __syncthreads();
  const int wv = t >> 6, lane = t & 63, lm = lane & 15, quad = lane >> 4;
  #pragma unroll
  for (int half=0; half<2; half++){
    const u16 (*in)[136] = half ? (const u16(*)[136])hs : (const u16(*)[136])xs;
    const u16* Wb = Wg1 + (size_t)half*384*128;
    #pragma unroll
    for (int rs=0; rs<6; rs++){
      f32x4 acc[4];
      #pragma unroll
      for (int nt=0; nt<4; nt++){ f32x4 z={0.f,0.f,0.f,0.f}; acc[nt]=z; }
      #pragma unroll
      for (int k0=0; k0<128; k0+=32){
        short8 bfr[4];
        #pragma unroll
        for (int nt=0; nt<4; nt++)
          bfr[nt] = *(const short8*)&in[nt*16+lm][k0 + quad*8];
        const short8 afr = *(const short8*)(Wb + ((size_t)(wv*96 + rs*16 + lm))*128 + k0 + quad*8);
        #pragma unroll
        for (int nt=0; nt<4; nt++)
          acc[nt] = __builtin_amdgcn_mfma_f32_16x16x32_bf16(afr, bfr[nt], acc[nt], 0,0,0);
      }
      #pragma unroll
      for (int nt=0; nt<4; nt++){
        const int n = n0 + nt*16 + lm;
        *(f32x4*)(G + ((size_t)(b*256 + n))*768 + half*384 + wv*96 + rs*16 + quad*4) = acc[nt];
      }
    }
  }
}

// ---------------------------------------------------------------------------
// GRU elementwise + readout. n>0: gates from G (set-1). n==0: direct GEMV set-0.
__global__ __launch_bounds__(128) void k5b_kernel(
    const float* __restrict__ G, const float* __restrict__ msum,
    const float* __restrict__ nf,
    const float* __restrict__ Wih0, const float* __restrict__ Whh0,
    const float* __restrict__ bih0, const float* __restrict__ bhh0,
    const float* __restrict__ bih1, const float* __restrict__ bhh1,
    const float* __restrict__ Wr0, const float* __restrict__ br0,
    const float* __restrict__ Wr1, const float* __restrict__ br1,
    float* __restrict__ outp)
{
  const int blk = blockIdx.x, b = blk >> 8, n = blk & 255;
  __shared__ float gl[768];
  __shared__ float xsh[128], hsh[128], hnew[128], lg[16];
  const int t = threadIdx.x;
  hsh[t] = nf[((size_t)(b*CH + t))*256 + n];
  float gi[3], gh[3];
  if (n == 0){
    xsh[t] = msum[((size_t)(b*256 + n))*CH + t];
    __syncthreads();
    #pragma unroll
    for (int prt=0; prt<3; prt++){
      int row = prt*128 + t;
      const float* wi_ = Wih0 + (size_t)row*CH;
      const float* wh_ = Whh0 + (size_t)row*CH;
      float si = 0.f, sh2 = 0.f;
      for (int k=0; k<128; k+=4){
        f32x4 wv1 = *(const f32x4*)(wi_ + k);
        f32x4 wv2 = *(const f32x4*)(wh_ + k);
        #pragma unroll
        for (int j=0; j<4; j++){ si += wv1[j]*xsh[k+j]; sh2 += wv2[j]*hsh[k+j]; }
      }
      gi[prt] = si + bih0[row];
      gh[prt] = sh2 + bhh0[row];
    }
  } else {
    #pragma unroll
    for (int p=0; p<6; p++) gl[p*128 + t] = G[((size_t)(b*256 + n))*768 + p*128 + t];
    __syncthreads();
    #pragma unroll
    for (int prt=0; prt<3; prt++){
      gi[prt] = gl[prt*128 + t] + bih1[prt*128 + t];
      gh[prt] = gl[384 + prt*128 + t] + bhh1[prt*128 + t];
    }
  }
  float r  = sigm(gi[0] + gh[0]);
  float z  = sigm(gi[1] + gh[1]);
  float ng = tanh_f(gi[2] + r*gh[2]);
  hnew[t] = (1.f - z)*ng + z*hsh[t];
  __syncthreads();
  const int K = n ? 12 : 10;
  const float* Wr = n ? Wr1 : Wr0;  const float* br = n ? br1 : br0;
  if (t < K){
    const float* wr_ = Wr + (size_t)t*CH;
    float s = 0.f;
    for (int k=0; k<128; k+=4){
      f32x4 wv1 = *(const f32x4*)(wr_ + k);
      #pragma unroll
      for (int j=0; j<4; j++) s += wv1[j]*hnew[k+j];
    }
    lg[t] = s + br[t];
  }
  __syncthreads();
  if (t < 12){
    float o = 0.f;
    if (t < K){
      float mx = -1e30f;
      for (int j=0; j<K; j++) mx = fmaxf(mx, lg[j]);
      float se = 0.f;
      for (int j=0; j<K; j++) se += __expf(lg[j] - mx);
      o = lg[t] - mx - __logf(se);
    }
    outp[((size_t)(b*256 + n))*12 + t] = o;
  }
}

// ---------------------------------------------------------------------------
extern "C" void kernel_launch(void* const* d_in, const int* in_sizes, int n_in,
                              void* d_out, int out_size, void* d_ws, size_t ws_size,
                              hipStream_t stream)
{
  (void)in_sizes; (void)n_in; (void)out_size; (void)ws_size;
  const float* edge = (const float*)d_in[0];
  const float* nf   = (const float*)d_in[1];
  const float* Wl0  = (const float*)d_in[5];
  const float* bl0  = (const float*)d_in[6];
  const float* Wl1  = (const float*)d_in[7];
  const float* bl1  = (const float*)d_in[8];
  const float* Wlo  = (const float*)d_in[9];
  const float* blo  = (const float*)d_in[10];
  const float* Wmsg = (const float*)d_in[11];
  const float* bmsg = (const float*)d_in[12];
  const float* Wih0 = (const float*)d_in[13];
  const float* Whh0 = (const float*)d_in[14];
  const float* bih0 = (const float*)d_in[15];
  const float* bhh0 = (const float*)d_in[16];
  const float* Wih1 = (const float*)d_in[17];
  const float* Whh1 = (const float*)d_in[18];
  const float* bih1 = (const float*)d_in[19];
  const float* bhh1 = (const float*)d_in[20];
  const float* Wr0  = (const float*)d_in[21];
  const float* br0  = (const float*)d_in[22];
  const float* Wr1  = (const float*)d_in[23];
  const float* br1  = (const float*)d_in[24];

  char* ws = (char*)d_ws;
  float* A1v   = (float*)(ws);                       // [0,       1048576)
  float* A2nat = (float*)(ws + 1048576);             // [1048576, 2097152)
  float* U     = (float*)(ws + 2097152);             // [2097152, 2621440)
  float* V     = (float*)(ws + 2621440);             // [2621440, 3145728)
  float* msum  = (float*)(ws + 3145728);             // [3145728, 3670016)
  float* s_e   = (float*)(ws + 3670016);             // [3670016, 4194304)
  float* sAr   = (float*)(ws + 4194304);             // [4194304, 4198400)
  u16*   W0c   = (u16*)(ws + 4198400);               // [4198400, 4296704)
  u16*   W1c   = (u16*)(ws + 4296704);               // [4296704, 4395008)
  u16*   Wmc   = (u16*)(ws + 4395008);               // [4395008, 4427776)
  float* b0c   = (float*)(ws + 4427776);             // [4427776, 4429312)
  float* b1c   = (float*)(ws + 4429312);             // [4429312, 4430848)
  u16*   Wuv   = (u16*)(ws + 4430848);               // [4430848, 4496384)
  u16*   Wg1   = (u16*)(ws + 4496384);               // [4496384, 4692992)
  float* W3T   = (float*)(ws + 4692992);             // [4692992, 4758528)
  // G (3 MB, fp32) overlays A1v/A2nat/U/V — all dead once gg_kernel runs.
  float* G     = (float*)(ws);

  float* outA = (float*)d_out;
  float* outP = outA + (size_t)PIXTOT;

  wcvt_kernel<<<dim3(384), dim3(256), 0, stream>>>(
      Wl0, bl0, Wl1, bl1, Wmsg, Wih1, Whh1,
      W0c, W1c, b0c, b1c, Wmc, W3T, Wuv, Wg1);
  uvmfma_kernel<<<dim3(16), dim3(256), 0, stream>>>(nf, Wuv, bmsg, U, V);
  link_kernel<0><<<dim3(PIXTOT/64), dim3(256), 0, stream>>>(
      edge, (const float*)nullptr, U, V, Wmc, W0c, b0c, W1c, b1c, Wlo, blo,
      A1v, (float*)nullptr, (float*)nullptr);
  link_kernel<1><<<dim3(PIXTOT/64), dim3(256), 0, stream>>>(
      edge, A1v, U, V, Wmc, W0c, b0c, W1c, b1c, Wlo, blo,
      A1v, outA, A2nat);
  se_kernel<<<dim3(4*256), dim3(256), 0, stream>>>(edge, A2nat, s_e, sAr);
  mfinal_kernel<<<dim3(4*256), dim3(128), 0, stream>>>(
      s_e, sAr, A2nat, V, W3T, U, msum);
  gg_kernel<<<dim3(16), dim3(256), 0, stream>>>(msum, nf, Wg1, G);
  k5b_kernel<<<dim3(4*256), dim3(128), 0, stream>>>(
      G, msum, nf, Wih0, Whh0, bih0, bhh0, bih1, bhh1,
      Wr0, br0, Wr1, br1, outP);
}